// Round 2
// baseline (2222.128 us; speedup 1.0000x reference)
//
#include <hip/hip_runtime.h>
#include <cstddef>

// SkipGRU on MI355X (gfx950) — fused per-step [x_t | h] @ [[W],[U]] + gates.
// B=128,T=512,C=512,H=512 -> N=4096 seqs of len 16.
//
// Round-2 structure:
//  - x pre-packed to bf16 in fragment-ordered tiles: xb_t[t][nblk(64)][kt(16)][g(4)][row(64)][8]
//    (K-chunk = 32, granule = 8 bf16 = 16B). Same tiling for Bp_t and h ping-pong buffers.
//  - gru_fused: block = 64n x 384 gemm-cols (128 h-cols x 3 gates), grid (64,4), 256 thr,
//    4 waves 2x2, wave = 32n x 192c. K=1024 (phase0 k<512 = x@W, phase1 = h@U).
//  - Staging via __builtin_amdgcn_global_load_lds (16B), double-buffered LDS
//    (2 x 28KB), raw s_waitcnt vmcnt(7)/s_barrier pipeline so back-buffer loads
//    stay in flight across the barrier.
//  - Epilogue: gates in regs (C/D layout col=lane&15,row=quad*4+reg), h written in
//    tiled layout via LDS transpose; last step writes fp32 out directly.

typedef unsigned short u16;
typedef __attribute__((ext_vector_type(8))) short short8;
typedef __attribute__((ext_vector_type(8))) u16 u16x8;
typedef __attribute__((ext_vector_type(4))) float floatx4;

#define MFMA16(a, b, c) __builtin_amdgcn_mfma_f32_16x16x32_bf16((a), (b), (c), 0, 0, 0)

__device__ __forceinline__ u16 f32_to_bf16(float f) {
  union { float f; unsigned int u; } c; c.f = f;
  unsigned int u = c.u + 0x7FFFu + ((c.u >> 16) & 1u);  // RNE
  return (u16)(u >> 16);
}
__device__ __forceinline__ float bf16_to_f32(u16 v) {
  union { unsigned int u; float f; } c; c.u = ((unsigned int)v) << 16;
  return c.f;
}
__device__ __forceinline__ float sigmoidf_(float x) {
  return 1.0f / (1.0f + __expf(-x));
}
__device__ __forceinline__ void gload_lds16(const void* g, void* l) {
  __builtin_amdgcn_global_load_lds(
      (const __attribute__((address_space(1))) unsigned int*)g,
      (__attribute__((address_space(3))) unsigned int*)l, 16, 0, 0);
}
__device__ __forceinline__ void wait_vm7() { asm volatile("s_waitcnt vmcnt(7)" ::: "memory"); }
__device__ __forceinline__ void wait_vm0() { asm volatile("s_waitcnt vmcnt(0)" ::: "memory"); }
__device__ __forceinline__ void barrier_raw() { asm volatile("s_barrier" ::: "memory"); }

// ---------------------------------------------------------------------------
// pack_x: x fp32 (128,512,512) -> xb_t bf16 tiled [t][nblk][kt(16)][g(4)][row(64)][8]
// row n = b*32+s within nblk*64+row; source x[b][t*32+s][kt*32+g*8 ..]
// 4,194,304 granules, 1/thread. Writes perfectly coalesced.
// ---------------------------------------------------------------------------
__global__ void pack_x(const float* __restrict__ x, u16* __restrict__ xb) {
  size_t gid = (size_t)blockIdx.x * 256 + threadIdx.x;
  int row  = (int)(gid & 63);
  int g    = (int)((gid >> 6) & 3);
  int kt   = (int)((gid >> 8) & 15);
  int nblk = (int)((gid >> 12) & 63);
  int t    = (int)(gid >> 18);
  int n = nblk * 64 + row, b = n >> 5, s = n & 31;
  const float* src = x + ((size_t)(b * 512 + t * 32 + s) * 512 + kt * 32 + g * 8);
  floatx4 va = *(const floatx4*)src;
  floatx4 vb = *(const floatx4*)(src + 4);
  u16x8 pk;
  pk[0] = f32_to_bf16(va[0]); pk[1] = f32_to_bf16(va[1]);
  pk[2] = f32_to_bf16(va[2]); pk[3] = f32_to_bf16(va[3]);
  pk[4] = f32_to_bf16(vb[0]); pk[5] = f32_to_bf16(vb[1]);
  pk[6] = f32_to_bf16(vb[2]); pk[7] = f32_to_bf16(vb[3]);
  *(u16x8*)(xb + gid * 8) = pk;
}

// ---------------------------------------------------------------------------
// pack_Bt: [W;U] -> Bp_t bf16 tiled [cchunk(12)][kt(32)][g(4)][col(128)][8]
// gemm col c = cchunk*128+col; k = kt*32+g*8+j; value = k<512 ? W[k][c] : U[k-512][c]
// 196,608 granules. Reads coalesced across col per j; writes coalesced.
// ---------------------------------------------------------------------------
__global__ void pack_Bt(const float* __restrict__ W, const float* __restrict__ U,
                        u16* __restrict__ Bt) {
  size_t gid = (size_t)blockIdx.x * 256 + threadIdx.x;
  int col = (int)(gid & 127);
  int g   = (int)((gid >> 7) & 3);
  int kt  = (int)((gid >> 9) & 31);
  int cc  = (int)(gid >> 14);
  int c = cc * 128 + col;
  int k0 = kt * 32 + g * 8;
  u16x8 pk;
#pragma unroll
  for (int j = 0; j < 8; ++j) {
    int k = k0 + j;
    float v = (k < 512) ? W[(size_t)k * 1536 + c] : U[(size_t)(k - 512) * 1536 + c];
    pk[j] = f32_to_bf16(v);
  }
  *(u16x8*)(Bt + gid * 8) = pk;
}

// ---------------------------------------------------------------------------
// gru_fused: one GRU step. Grid (64,4): nb over 4096/64, hb over 512/128 h-cols.
// 256 threads = 4 waves (wy,wx); wave = 32n x 192c. K-chunk = 32, 32 chunks.
// LDS: 2 buffers x (A 4KB [g4][row64][16B] + B 24KB 3x[g4][col128][16B]).
// h buffers use the same tiled layout as xb_t per nblk: [nblk][kt16][g4][row64][8].
// ---------------------------------------------------------------------------
__global__ __launch_bounds__(256)
void gru_fused(const u16* __restrict__ xb_t, const u16* __restrict__ Bp_t,
               const float* __restrict__ bias,
               const u16* __restrict__ ht_in, u16* __restrict__ ht_out,
               float* __restrict__ out, int t, int first, int last) {
  __shared__ char sm[57344];  // 2 x 28672
  const int tid = threadIdx.x;
  const int nb = blockIdx.x;   // 0..63
  const int hb = blockIdx.y;   // 0..3
  const int w = tid >> 6;
  const int lane = tid & 63;
  const int wy = w >> 1, wx = w & 1;
  const int q = lane >> 4, lc = lane & 15;

  const char* xbBase = (const char*)xb_t + (size_t)(t * 64 + nb) * 65536;
  const char* htBase = (const char*)ht_in + (size_t)nb * 65536;
  const int cs0 = hb, cs1 = 4 + hb, cs2 = 8 + hb;  // z / r / h-gate col-chunks

  floatx4 acZ[2][4] = {{{0.f,0.f,0.f,0.f},{0.f,0.f,0.f,0.f},{0.f,0.f,0.f,0.f},{0.f,0.f,0.f,0.f}},
                       {{0.f,0.f,0.f,0.f},{0.f,0.f,0.f,0.f},{0.f,0.f,0.f,0.f},{0.f,0.f,0.f,0.f}}};
  floatx4 acR[2][4] = {{{0.f,0.f,0.f,0.f},{0.f,0.f,0.f,0.f},{0.f,0.f,0.f,0.f},{0.f,0.f,0.f,0.f}},
                       {{0.f,0.f,0.f,0.f},{0.f,0.f,0.f,0.f},{0.f,0.f,0.f,0.f},{0.f,0.f,0.f,0.f}}};
  floatx4 acX[2][4] = {{{0.f,0.f,0.f,0.f},{0.f,0.f,0.f,0.f},{0.f,0.f,0.f,0.f},{0.f,0.f,0.f,0.f}},
                       {{0.f,0.f,0.f,0.f},{0.f,0.f,0.f,0.f},{0.f,0.f,0.f,0.f},{0.f,0.f,0.f,0.f}}};
  floatx4 acH[2][4] = {{{0.f,0.f,0.f,0.f},{0.f,0.f,0.f,0.f},{0.f,0.f,0.f,0.f},{0.f,0.f,0.f,0.f}},
                       {{0.f,0.f,0.f,0.f},{0.f,0.f,0.f,0.f},{0.f,0.f,0.f,0.f},{0.f,0.f,0.f,0.f}}};

  const int ktall = first ? 16 : 32;

  // Stage K-chunk kt into buffer bsel: 28 x 1KB wave-instrs, 7 per wave.
  auto stage = [&](int kt, int bsel) {
    char* ldsA = sm + bsel * 28672;
    char* ldsB = ldsA + 4096;
    const char* aS = (kt < 16) ? (xbBase + (size_t)kt * 4096)
                               : (htBase + (size_t)(kt - 16) * 4096);
#pragma unroll
    for (int j = 0; j < 7; ++j) {
      int s = w * 7 + j;
      if (s < 4) {
        gload_lds16(aS + s * 1024 + lane * 16, ldsA + s * 1024);
      } else {
        int ib = s - 4;                 // 0..23
        int ch = ib >> 3;               // chunk 0..2
        int cs = (ch == 0) ? cs0 : ((ch == 1) ? cs1 : cs2);
        gload_lds16((const char*)Bp_t + (size_t)cs * 262144 + (size_t)kt * 8192
                        + (size_t)(ib & 7) * 1024 + lane * 16,
                    ldsB + ib * 1024);
      }
    }
  };

  // Compute one K-chunk from buffer bsel; third-gate acc passed in (acX or acH).
  auto compute = [&](int bsel, floatx4 (&acT)[2][4]) {
    const char* ldsA = sm + bsel * 28672;
    const char* ldsB = ldsA + 4096;
    short8 a0 = *(const short8*)(ldsA + (q * 64 + wy * 32 + lc) * 16);
    short8 a1 = *(const short8*)(ldsA + (q * 64 + wy * 32 + 16 + lc) * 16);
#pragma unroll
    for (int ci = 0; ci < 4; ++ci) {
      int co = (q * 128 + wx * 64 + ci * 16 + lc) * 16;
      short8 bz = *(const short8*)(ldsB + co);
      short8 br = *(const short8*)(ldsB + 8192 + co);
      short8 bh = *(const short8*)(ldsB + 16384 + co);
      acZ[0][ci] = MFMA16(a0, bz, acZ[0][ci]);
      acZ[1][ci] = MFMA16(a1, bz, acZ[1][ci]);
      acR[0][ci] = MFMA16(a0, br, acR[0][ci]);
      acR[1][ci] = MFMA16(a1, br, acR[1][ci]);
      acT[0][ci] = MFMA16(a0, bh, acT[0][ci]);
      acT[1][ci] = MFMA16(a1, bh, acT[1][ci]);
    }
  };

  stage(0, 0);
  for (int kt = 0; kt < 16; ++kt) {           // phase 0: x @ W  (third gate -> acX)
    if (kt + 1 < ktall) { stage(kt + 1, (kt + 1) & 1); wait_vm7(); }
    else wait_vm0();
    barrier_raw();
    compute(kt & 1, acX);
    barrier_raw();
  }
  if (!first) {
    for (int kt = 16; kt < 32; ++kt) {        // phase 1: h @ U  (third gate -> acH)
      if (kt + 1 < 32) { stage(kt + 1, (kt + 1) & 1); wait_vm7(); }
      else wait_vm0();
      barrier_raw();
      compute(kt & 1, acH);
      barrier_raw();
    }
  }

  // ---- Epilogue: gates. C/D layout: col = lane&15, row = quad*4 + reg ----
  const float* b0 = bias;
  const float* b1 = bias + 1536;
  u16* Ct = (u16*)sm;  // 64 x 136 u16 (17KB) in buffer 0 (last compute used buffer 1)
#pragma unroll
  for (int ci = 0; ci < 4; ++ci) {
    const int hcl = wx * 64 + ci * 16 + lc;   // 0..127 (local h-col)
    const int hg = hb * 128 + hcl;            // 0..511
    const float bz = b0[hg] + b1[hg];
    const float br = b0[512 + hg] + b1[512 + hg];
    const float b0h = b0[1024 + hg];
    const float b1h = b1[1024 + hg];
    const int ktg = hg >> 5;
    const int gg = (hg >> 3) & 3;
    const size_t gbase = (((size_t)nb * 16 + ktg) * 4 + gg) * 64;  // h_t granule base
#pragma unroll
    for (int mi = 0; mi < 2; ++mi) {
#pragma unroll
      for (int reg = 0; reg < 4; ++reg) {
        const int nl = wy * 32 + mi * 16 + q * 4 + reg;   // 0..63
        const int n = nb * 64 + nl;
        float z = sigmoidf_(acZ[mi][ci][reg] + bz);
        float r = sigmoidf_(acR[mi][ci][reg] + br);
        float hh = acX[mi][ci][reg] + b0h + r * (acH[mi][ci][reg] + b1h);
        hh = fmaxf(hh, 0.0f);
        float hp = 0.0f;
        if (!first) hp = bf16_to_f32(ht_in[(gbase + nl) * 8 + (hg & 7)]);
        float v = z * hp + (1.0f - z) * hh;
        if (last) out[(size_t)n * 512 + hg] = v;
        else      Ct[nl * 136 + hcl] = f32_to_bf16(v);
      }
    }
  }
  if (!last) {
    __syncthreads();
    // Re-emit h in tiled layout: block covers kt-local 0..3 (h-cols hb*128..+128).
#pragma unroll
    for (int i = 0; i < 4; ++i) {
      int idx = i * 256 + tid;        // 0..1023
      int row = idx & 63;
      int g = (idx >> 6) & 3;
      int ktl = idx >> 8;             // 0..3
      u16x8 vv = *(const u16x8*)(Ct + row * 136 + ktl * 32 + g * 8);
      *(u16x8*)(ht_out + ((((size_t)nb * 16 + hb * 4 + ktl) * 4 + g) * 64 + row) * 8) = vv;
    }
  }
}

// ---------------------------------------------------------------------------
extern "C" void kernel_launch(void* const* d_in, const int* in_sizes, int n_in,
                              void* d_out, int out_size, void* d_ws, size_t ws_size,
                              hipStream_t stream) {
  const float* x = (const float*)d_in[0];    // (128,512,512)
  const float* W = (const float*)d_in[1];    // (512,1536)
  const float* U = (const float*)d_in[2];    // (512,1536)
  const float* bias = (const float*)d_in[3]; // (2,1536)
  float* out = (float*)d_out;                // (128,16384)

  u16* xb_t = (u16*)d_ws;                        // 65536*512 bf16 = 64 MB
  u16* Bp_t = xb_t + (size_t)65536 * 512;        // 12*32*4*128*8 = 3 MB
  u16* h0 = Bp_t + (size_t)1536 * 1024;          // 4096*512 bf16 = 4 MB
  u16* h1 = h0 + (size_t)4096 * 512;             // 4 MB

  pack_x<<<16384, 256, 0, stream>>>(x, xb_t);
  pack_Bt<<<768, 256, 0, stream>>>(W, U, Bp_t);

  for (int t = 0; t < 16; ++t) {
    const u16* hin = (t & 1) ? h1 : h0;          // t=0 never reads h
    u16* hout = (t & 1) ? h0 : h1;
    gru_fused<<<dim3(64, 4), 256, 0, stream>>>(
        xb_t, Bp_t, bias, hin, hout, out, t, (t == 0) ? 1 : 0, (t == 15) ? 1 : 0);
  }
}

// Round 3
// 558.800 us; speedup vs baseline: 3.9766x; 3.9766x over previous
//
#include <hip/hip_runtime.h>
#include <cstddef>

// SkipGRU on MI355X (gfx950) — round 3.
// Per step t: [x_t | h] (4096x1024) @ [[W],[U]] (1024x1536) fused with GRU gates.
//
// Structure (reverted to proven round-1 residency + round-2 packing):
//  - x pre-packed bf16, fragment-ordered: xb[t][nb(64)][kt(16)][g(4)][row(64)][8]
//  - B pre-packed bf16: Bt[cc(24 x 64cols)][kt(32)][g(4)][col(64)][8]
//  - h ping-pong in same granule layout as xb (per nb: [kt16][g4][row64][8]).
//  - gru_step: tile 64n x 192c (3 gates x 64 h-cols), grid 512 (2 blocks/CU),
//    256 thr = 4 waves 2x2 (wave = 32n x 96c). K-chunk 32, 32 chunks.
//    Staging via global_load_lds 16B, double-buffered 2x16KB LDS, m97 pipeline:
//    stage(k+1); compute(k); __syncthreads().  (compiler-managed waitcnt)
//  - XCD swizzle: the 8 hb-blocks sharing one nb land on one XCD (idx%8 = nb%8)
//    so that nb's x/h slice is L2-resident on that XCD.

typedef unsigned short u16;
typedef __attribute__((ext_vector_type(8))) short short8;
typedef __attribute__((ext_vector_type(8))) u16 u16x8;
typedef __attribute__((ext_vector_type(4))) float floatx4;

#define MFMA16(a, b, c) __builtin_amdgcn_mfma_f32_16x16x32_bf16((a), (b), (c), 0, 0, 0)

__device__ __forceinline__ u16 f32_to_bf16(float f) {
  union { float f; unsigned int u; } c; c.f = f;
  unsigned int u = c.u + 0x7FFFu + ((c.u >> 16) & 1u);  // RNE
  return (u16)(u >> 16);
}
__device__ __forceinline__ float bf16_to_f32(u16 v) {
  union { unsigned int u; float f; } c; c.u = ((unsigned int)v) << 16;
  return c.f;
}
__device__ __forceinline__ float sigmoidf_(float x) {
  return 1.0f / (1.0f + __expf(-x));
}
__device__ __forceinline__ void gload_lds16(const void* g, void* l) {
  __builtin_amdgcn_global_load_lds(
      (const __attribute__((address_space(1))) unsigned int*)g,
      (__attribute__((address_space(3))) unsigned int*)l, 16, 0, 0);
}

// ---------------------------------------------------------------------------
// pack_x: x fp32 (128,512,512) -> xb bf16 [t][nb(64)][kt(16)][g(4)][row(64)][8]
// row n = nb*64+row; n = b*32+s; source x[b][t*32+s][kt*32+g*8 ..]
// ---------------------------------------------------------------------------
__global__ void pack_x(const float* __restrict__ x, u16* __restrict__ xb) {
  size_t gid = (size_t)blockIdx.x * 256 + threadIdx.x;
  int row  = (int)(gid & 63);
  int g    = (int)((gid >> 6) & 3);
  int kt   = (int)((gid >> 8) & 15);
  int nblk = (int)((gid >> 12) & 63);
  int t    = (int)(gid >> 18);
  int n = nblk * 64 + row, b = n >> 5, s = n & 31;
  const float* src = x + ((size_t)(b * 512 + t * 32 + s) * 512 + kt * 32 + g * 8);
  floatx4 va = *(const floatx4*)src;
  floatx4 vb = *(const floatx4*)(src + 4);
  u16x8 pk;
  pk[0] = f32_to_bf16(va[0]); pk[1] = f32_to_bf16(va[1]);
  pk[2] = f32_to_bf16(va[2]); pk[3] = f32_to_bf16(va[3]);
  pk[4] = f32_to_bf16(vb[0]); pk[5] = f32_to_bf16(vb[1]);
  pk[6] = f32_to_bf16(vb[2]); pk[7] = f32_to_bf16(vb[3]);
  *(u16x8*)(xb + gid * 8) = pk;
}

// ---------------------------------------------------------------------------
// pack_Bt: [W;U] -> Bt bf16 [cc(24)][kt(32)][g(4)][col(64)][8]
// gemm col c = cc*64+col; k = kt*32+g*8+j; value = k<512 ? W[k][c] : U[k-512][c]
// ---------------------------------------------------------------------------
__global__ void pack_Bt(const float* __restrict__ W, const float* __restrict__ U,
                        u16* __restrict__ Bt) {
  size_t gid = (size_t)blockIdx.x * 256 + threadIdx.x;   // < 196608
  int col = (int)(gid & 63);
  int g   = (int)((gid >> 6) & 3);
  int kt  = (int)((gid >> 8) & 31);
  int cc  = (int)(gid >> 13);
  int c = cc * 64 + col;
  int k0 = kt * 32 + g * 8;
  u16x8 pk;
#pragma unroll
  for (int j = 0; j < 8; ++j) {
    int k = k0 + j;
    float v = (k < 512) ? W[(size_t)k * 1536 + c] : U[(size_t)(k - 512) * 1536 + c];
    pk[j] = f32_to_bf16(v);
  }
  *(u16x8*)(Bt + gid * 8) = pk;
}

// ---------------------------------------------------------------------------
// gru_step: one GRU timestep.
// Grid 512 linear, swizzled: nb = (idx>>6)*8 + (idx&7), hb = (idx>>3)&7.
// Block tile 64n x 192c; 4 waves (wy,wx); wave = 32n x (3 gates x 32 h-cols).
// LDS: 2 x 16KB (A 4KB [g4][row64][16B] + B 3 x 4KB [g4][col64][16B]).
// ---------------------------------------------------------------------------
__global__ __launch_bounds__(256)
void gru_step(const u16* __restrict__ xb, const u16* __restrict__ Bt,
              const float* __restrict__ bias,
              const u16* __restrict__ h_in, u16* __restrict__ h_out,
              float* __restrict__ out, int t, int first, int last) {
  __shared__ alignas(16) char sm[32768];
  const int tid = threadIdx.x;
  const int idx = blockIdx.x;
  const int nb = ((idx >> 6) << 3) | (idx & 7);   // 0..63
  const int hb = (idx >> 3) & 7;                  // 0..7
  const int w = tid >> 6;
  const int lane = tid & 63;
  const int wy = w >> 1, wx = w & 1;
  const int q = lane >> 4, lc = lane & 15;

  const u16* xbB = xb + (size_t)(t * 64 + nb) * 32768;
  const u16* htB = h_in + (size_t)nb * 32768;
  const int cs0 = hb, cs1 = 8 + hb, cs2 = 16 + hb;   // z / r / h-gate col-chunks

  floatx4 acZ[2][2] = {{{0.f,0.f,0.f,0.f},{0.f,0.f,0.f,0.f}},{{0.f,0.f,0.f,0.f},{0.f,0.f,0.f,0.f}}};
  floatx4 acR[2][2] = {{{0.f,0.f,0.f,0.f},{0.f,0.f,0.f,0.f}},{{0.f,0.f,0.f,0.f},{0.f,0.f,0.f,0.f}}};
  floatx4 acX[2][2] = {{{0.f,0.f,0.f,0.f},{0.f,0.f,0.f,0.f}},{{0.f,0.f,0.f,0.f},{0.f,0.f,0.f,0.f}}};
  floatx4 acH[2][2] = {{{0.f,0.f,0.f,0.f},{0.f,0.f,0.f,0.f}},{{0.f,0.f,0.f,0.f},{0.f,0.f,0.f,0.f}}};

  const int ktall = first ? 16 : 32;
  const int wo = w * 1024;   // per-wave byte slot within each 4KB panel

  // Stage K-chunk kt (A 4KB + 3 gate-B 4KB) into buffer bsel. 4 glds16/thread.
  auto stage = [&](int kt, int bsel) {
    char* lds = sm + bsel * 16384;
    const char* aS = (const char*)((kt < 16) ? (xbB + (size_t)kt * 2048)
                                             : (htB + (size_t)(kt - 16) * 2048));
    gload_lds16(aS + wo + lane * 16, lds + wo);
    gload_lds16((const char*)(Bt + (size_t)(cs0 * 32 + kt) * 2048) + wo + lane * 16,
                lds + 4096 + wo);
    gload_lds16((const char*)(Bt + (size_t)(cs1 * 32 + kt) * 2048) + wo + lane * 16,
                lds + 8192 + wo);
    gload_lds16((const char*)(Bt + (size_t)(cs2 * 32 + kt) * 2048) + wo + lane * 16,
                lds + 12288 + wo);
  };

  // Compute one K-chunk from buffer bsel; third-gate acc is acX (phase0) / acH.
  auto compute = [&](int bsel, floatx4 (&acT)[2][2]) {
    const char* lds = sm + bsel * 16384;
    short8 a0 = *(const short8*)(lds + (q * 64 + wy * 32 + lc) * 16);
    short8 a1 = *(const short8*)(lds + (q * 64 + wy * 32 + 16 + lc) * 16);
#pragma unroll
    for (int ci = 0; ci < 2; ++ci) {
      int co = (q * 64 + wx * 32 + ci * 16 + lc) * 16;
      short8 bz = *(const short8*)(lds + 4096 + co);
      short8 br = *(const short8*)(lds + 8192 + co);
      short8 bh = *(const short8*)(lds + 12288 + co);
      acZ[0][ci] = MFMA16(a0, bz, acZ[0][ci]);
      acZ[1][ci] = MFMA16(a1, bz, acZ[1][ci]);
      acR[0][ci] = MFMA16(a0, br, acR[0][ci]);
      acR[1][ci] = MFMA16(a1, br, acR[1][ci]);
      acT[0][ci] = MFMA16(a0, bh, acT[0][ci]);
      acT[1][ci] = MFMA16(a1, bh, acT[1][ci]);
    }
  };

  stage(0, 0);
  __syncthreads();
  for (int kt = 0; kt < 16; ++kt) {            // phase 0: x @ W  (3rd gate -> acX)
    if (kt + 1 < ktall) stage(kt + 1, (kt + 1) & 1);
    compute(kt & 1, acX);
    __syncthreads();
  }
  if (!first) {
    for (int kt = 16; kt < 32; ++kt) {         // phase 1: h @ U  (3rd gate -> acH)
      if (kt + 1 < 32) stage(kt + 1, (kt + 1) & 1);
      compute(kt & 1, acH);
      __syncthreads();
    }
  }

  // ---- Epilogue. C/D layout: col = lane&15, row = quad*4 + reg ----
  const float* b0 = bias;
  const float* b1 = bias + 1536;
  u16* Ct = (u16*)sm;    // 64 rows x 72 u16 (9KB); all compute done (final barrier above)
#pragma unroll
  for (int ci = 0; ci < 2; ++ci) {
    const int hcl = wx * 32 + ci * 16 + lc;    // 0..63
    const int hg = hb * 64 + hcl;              // 0..511
    const float bz = b0[hg] + b1[hg];
    const float br = b0[512 + hg] + b1[512 + hg];
    const float b0h = b0[1024 + hg];
    const float b1h = b1[1024 + hg];
    const int ktg = hg >> 5;
    const int gg = (hg >> 3) & 3;
    const size_t hbase = (((size_t)nb * 16 + ktg) * 4 + gg) * 64;
#pragma unroll
    for (int mi = 0; mi < 2; ++mi) {
#pragma unroll
      for (int reg = 0; reg < 4; ++reg) {
        const int nl = wy * 32 + mi * 16 + q * 4 + reg;   // 0..63
        const int n = nb * 64 + nl;
        float z = sigmoidf_(acZ[mi][ci][reg] + bz);
        float r = sigmoidf_(acR[mi][ci][reg] + br);
        float hh = acX[mi][ci][reg] + b0h + r * (acH[mi][ci][reg] + b1h);
        hh = fmaxf(hh, 0.0f);
        float hp = 0.0f;
        if (!first) hp = bf16_to_f32(h_in[(hbase + nl) * 8 + (hg & 7)]);
        float v = z * hp + (1.0f - z) * hh;
        if (last) out[(size_t)n * 512 + hg] = v;
        else      Ct[nl * 72 + hcl] = f32_to_bf16(v);
      }
    }
  }
  if (!last) {
    __syncthreads();
    // Re-emit h in granule layout: 512 granules (row64 x g4 x ktl2), 2/thread.
#pragma unroll
    for (int i = 0; i < 2; ++i) {
      int e = i * 256 + tid;
      int row = e & 63;
      int g = (e >> 6) & 3;
      int ktl = e >> 8;                         // 0..1
      u16x8 vv = *(const u16x8*)(Ct + row * 72 + ktl * 32 + g * 8);
      *(u16x8*)(h_out + ((((size_t)nb * 16 + (hb * 2 + ktl)) * 4 + g) * 64 + row) * 8) = vv;
    }
  }
}

// ---------------------------------------------------------------------------
extern "C" void kernel_launch(void* const* d_in, const int* in_sizes, int n_in,
                              void* d_out, int out_size, void* d_ws, size_t ws_size,
                              hipStream_t stream) {
  const float* x = (const float*)d_in[0];    // (128,512,512)
  const float* W = (const float*)d_in[1];    // (512,1536)
  const float* U = (const float*)d_in[2];    // (512,1536)
  const float* bias = (const float*)d_in[3]; // (2,1536)
  float* out = (float*)d_out;                // (128,16384)

  u16* xb = (u16*)d_ws;                      // 16*64*32768 u16 = 64 MB
  u16* Bt = xb + (size_t)16 * 64 * 32768;    // 1536*1024 u16 = 3 MB
  u16* h0 = Bt + (size_t)1536 * 1024;        // 4096*512 u16 = 4 MB
  u16* h1 = h0 + (size_t)4096 * 512;         // 4 MB

  pack_x<<<16384, 256, 0, stream>>>(x, xb);
  pack_Bt<<<768, 256, 0, stream>>>(W, U, Bt);

  for (int t = 0; t < 16; ++t) {
    const u16* hin = (t & 1) ? h1 : h0;      // t=0 never reads h
    u16* hout = (t & 1) ? h0 : h1;
    gru_step<<<512, 256, 0, stream>>>(
        xb, Bt, bias, hin, hout, out, t, (t == 0) ? 1 : 0, (t == 15) ? 1 : 0);
  }
}